// Round 2
// baseline (7146.334 us; speedup 1.0000x reference)
//
#include <hip/hip_runtime.h>
#include <cstddef>

// Problem constants (from reference)
#define NB   64      // B
#define TB   512     // T
#define FB   512     // F
#define NPOI 100000

// ---------------------------------------------------------------------------
// 1. Transpose Whh[l] (g,f) -> WT[l] (f,g) so the scan's streamed reads are
//    coalesced (lane g reads WT[f*512+g]).
// ---------------------------------------------------------------------------
__global__ __launch_bounds__(1024)
void k_transpose(const float* __restrict__ Whh, float* __restrict__ WT)
{
    __shared__ float tile[32][33];
    const int l  = blockIdx.z;
    const int f0 = blockIdx.x * 32, g0 = blockIdx.y * 32;
    const int tx = threadIdx.x, ty = threadIdx.y;
    const size_t lo = (size_t)l * FB * FB;
    tile[ty][tx] = Whh[lo + (size_t)(g0 + ty) * FB + (f0 + tx)];
    __syncthreads();
    WT[lo + (size_t)(f0 + ty) * FB + (g0 + tx)] = tile[tx][ty];
}

// ---------------------------------------------------------------------------
// 2. Generic fp32 GEMM: C[M,N] = A[M,K] @ B[N,K]^T + bias[N]
//    EMBED: A row m is user_table[user[m],:] + poi_table[poi[m],:] (fused gather)
//    DUAL : also write C2 (tuple output duplication)
//    Tiles 64x64x16, 256 threads, 4x4 per-thread microtile.
//    M must be a multiple of 64 (true for all 3 uses); N tail guarded.
// ---------------------------------------------------------------------------
template<bool EMBED, bool DUAL>
__global__ __launch_bounds__(256)
void k_gemm_bt(const float* __restrict__ A,
               const int* __restrict__ uidx, const int* __restrict__ pidx,
               const float* __restrict__ utab, const float* __restrict__ ptab,
               const float* __restrict__ Bm, const float* __restrict__ bias,
               float* __restrict__ C, float* __restrict__ C2,
               int M, int N, int K)
{
    __shared__ __align__(16) float As[16][68];
    __shared__ __align__(16) float Bs[16][68];
    __shared__ int us[64], ps[64];

    const int tid = threadIdx.x;
    const int tn  = tid & 15, tm = tid >> 4;
    const int m0  = blockIdx.y * 64, n0 = blockIdx.x * 64;
    const int lr  = tid >> 2;          // tile row 0..63
    const int lc  = (tid & 3) * 4;     // k offset 0,4,8,12

    if (EMBED) {
        if (tid < 64) { us[tid] = uidx[m0 + tid]; ps[tid] = pidx[m0 + tid]; }
        __syncthreads();
    }

    float acc[4][4] = {};

    for (int k0 = 0; k0 < K; k0 += 16) {
        float4 a4, b4;
        if (EMBED) {
            const float4 u4 = *(const float4*)&utab[(size_t)us[lr] * K + k0 + lc];
            const float4 p4 = *(const float4*)&ptab[(size_t)ps[lr] * K + k0 + lc];
            a4 = make_float4(u4.x + p4.x, u4.y + p4.y, u4.z + p4.z, u4.w + p4.w);
        } else {
            a4 = *(const float4*)&A[(size_t)(m0 + lr) * K + k0 + lc];
        }
        const int nr = n0 + lr;
        if (nr < N) b4 = *(const float4*)&Bm[(size_t)nr * K + k0 + lc];
        else        b4 = make_float4(0.f, 0.f, 0.f, 0.f);

        __syncthreads();   // previous iteration's LDS reads complete
        As[lc + 0][lr] = a4.x; As[lc + 1][lr] = a4.y;
        As[lc + 2][lr] = a4.z; As[lc + 3][lr] = a4.w;
        Bs[lc + 0][lr] = b4.x; Bs[lc + 1][lr] = b4.y;
        Bs[lc + 2][lr] = b4.z; Bs[lc + 3][lr] = b4.w;
        __syncthreads();

        #pragma unroll
        for (int kk = 0; kk < 16; ++kk) {
            const float4 av4 = *(const float4*)&As[kk][tm * 4];
            const float4 bv4 = *(const float4*)&Bs[kk][tn * 4];
            const float av[4] = {av4.x, av4.y, av4.z, av4.w};
            const float bv[4] = {bv4.x, bv4.y, bv4.z, bv4.w};
            #pragma unroll
            for (int i = 0; i < 4; ++i)
                #pragma unroll
                for (int j = 0; j < 4; ++j)
                    acc[i][j] += av[i] * bv[j];
        }
    }

    const int cm = m0 + tm * 4, cn = n0 + tn * 4;
    #pragma unroll
    for (int i = 0; i < 4; ++i) {
        #pragma unroll
        for (int j = 0; j < 4; ++j) {
            const int n = cn + j;
            if (n < N) {
                const float v = acc[i][j] + bias[n];
                C[(size_t)(cm + i) * N + n] = v;
                if (DUAL) C2[(size_t)(cm + i) * N + n] = v;
            }
        }
    }
}

// ---------------------------------------------------------------------------
// 3. RNN scan, one workgroup per batch, 512 threads (lane = output unit g).
//    h_new = tanh(xw[t] + Whh @ h + bhh).  First NREG columns of Whh^T live in
//    registers, the rest stream from L2 every step. h double-buffered in LDS.
// ---------------------------------------------------------------------------
#define NREG 192

__global__ __launch_bounds__(512)
void k_scan(const float* __restrict__ WT,    // [FB][FB]  WT[f*FB+g] = Whh[g][f]
            const float* __restrict__ xw,    // [NB*TB, FB]
            const float* __restrict__ bhh,   // [FB]
            float* __restrict__ hout)        // [NB*TB, FB]
{
    const int g = threadIdx.x;
    const int b = blockIdx.x;
    __shared__ __align__(16) float hbuf[2][FB];

    float wr[NREG];
    #pragma unroll
    for (int j = 0; j < NREG; ++j) wr[j] = WT[(size_t)j * FB + g];
    const float bg = bhh[g];

    hbuf[0][g] = 0.f;
    __syncthreads();

    const float* xwb = xw   + (size_t)b * TB * FB;
    float*       hob = hout + (size_t)b * TB * FB;

    for (int t = 0; t < TB; ++t) {
        const float* hc = hbuf[t & 1];
        float acc = xwb[t * FB + g];

        #pragma unroll
        for (int j = 0; j < NREG; j += 4) {
            const float4 h4 = *(const float4*)&hc[j];
            acc += wr[j]     * h4.x + wr[j + 1] * h4.y
                 + wr[j + 2] * h4.z + wr[j + 3] * h4.w;
        }
        #pragma unroll 4
        for (int f = NREG; f < FB; f += 4) {
            const float4 h4 = *(const float4*)&hc[f];
            acc += WT[(size_t)(f + 0) * FB + g] * h4.x
                 + WT[(size_t)(f + 1) * FB + g] * h4.y
                 + WT[(size_t)(f + 2) * FB + g] * h4.z
                 + WT[(size_t)(f + 3) * FB + g] * h4.w;
        }

        const float hn = tanhf(acc + bg);
        hob[t * FB + g]       = hn;
        hbuf[(t + 1) & 1][g]  = hn;
        __syncthreads();
    }
}

// ---------------------------------------------------------------------------
// 4. Last-row spatio-temporal weights + weighted average over time.
//    Faithful fp32 reproduction of the reference formula (incl. the fp32
//    cancellation that makes the haversine factor collapse to 1).
// ---------------------------------------------------------------------------
__global__ __launch_bounds__(512)
void k_wavg(const float* __restrict__ h2,
            const float* __restrict__ lat, const float* __restrict__ lon,
            const float* __restrict__ ut,  float* __restrict__ outs)
{
    const int b = blockIdx.x, tid = threadIdx.x;
    __shared__ float wv[TB];
    __shared__ float red[TB];

    const float p = 0.017453292519943295f;          // pi/180 (rounds to fp32)
    const size_t base = (size_t)b * TB;
    const float la_i = lat[base + TB - 1], lo_i = lon[base + TB - 1], ti = ut[base + TB - 1];
    const float la_j = lat[base + tid],    lo_j = lon[base + tid],    tj = ut[base + tid];

    float a = 0.5f - cosf((la_i - la_j) * p) * 0.5f
            + cosf(la_i * p) * cosf(la_j * p) * (1.0f - cosf((lo_i - lo_j) * p)) * 0.5f;
    a = fminf(fmaxf(a, 0.f), 1.f);
    const float dis = (a > 0.f) ? 12742.0f * asinf(sqrtf(a)) : 0.f;
    const float dt  = fabsf(ti - tj);
    const float w = (1.0f + cosf(6.2831853071795864769f * dt)) * 0.5f
                  * expf(-0.01f * dt) * expf(-100.0f * dis) + 1e-10f;

    wv[tid] = w; red[tid] = w;
    __syncthreads();
    for (int s = 256; s > 0; s >>= 1) {
        if (tid < s) red[tid] += red[tid + s];
        __syncthreads();
    }
    const float inv = 1.0f / red[0];

    float acc = 0.f;
    const float* hb = h2 + (size_t)b * TB * FB;
    for (int j = 0; j < TB; ++j) acc += wv[j] * hb[j * FB + tid];
    outs[(size_t)b * FB + tid] = acc * inv;
}

// ---------------------------------------------------------------------------
// kernel_launch
//   inputs: 0 user 1 poi 2 cat 3 lat 4 lon 5 tod 6 dow 7 unixtime
//           8 user_table 9 poi_table 10 Wih 11 Whh 12 bih 13 bhh 14 W_lin 15 b_lin
//   (cat/tod/dow unused by the reference)
//   ws layout (floats): WT[2*512*512] | bufA[16.7M] | bufB[16.7M] | bufC[16.7M]
//                       | outs[64*512]   (~194 MiB total)
// ---------------------------------------------------------------------------
extern "C" void kernel_launch(void* const* d_in, const int* in_sizes, int n_in,
                              void* d_out, int out_size, void* d_ws, size_t ws_size,
                              hipStream_t stream)
{
    const int*   user = (const int*)d_in[0];
    const int*   poi  = (const int*)d_in[1];
    const float* lat  = (const float*)d_in[3];
    const float* lon  = (const float*)d_in[4];
    const float* ut   = (const float*)d_in[7];
    const float* utab = (const float*)d_in[8];
    const float* ptab = (const float*)d_in[9];
    const float* Wih  = (const float*)d_in[10];
    const float* Whh  = (const float*)d_in[11];
    const float* bih  = (const float*)d_in[12];
    const float* bhh  = (const float*)d_in[13];
    const float* Wlin = (const float*)d_in[14];
    const float* blin = (const float*)d_in[15];
    float* out = (float*)d_out;

    float* ws   = (float*)d_ws;
    const size_t big = (size_t)NB * TB * FB;        // 16,777,216
    float* WT   = ws;                               // 2*FB*FB
    float* bufA = WT + 2 * FB * FB;
    float* bufB = bufA + big;
    float* bufC = bufB + big;
    float* outs = bufC + big;                       // NB*FB

    // 1. Whh transposes (both layers)
    k_transpose<<<dim3(16, 16, 2), dim3(32, 32), 0, stream>>>(Whh, WT);

    // 2. xw1 = (user_emb + poi_emb) @ Wih0^T + bih0   -> bufA
    k_gemm_bt<true, false><<<dim3(8, 512), 256, 0, stream>>>(
        nullptr, user, poi, utab, ptab, Wih, bih, bufA, nullptr,
        NB * TB, FB, FB);

    // 3. scan layer 0: bufA -> bufB (h1 sequence)
    k_scan<<<64, 512, 0, stream>>>(WT, bufA, bhh, bufB);

    // 4. xw2 = h1 @ Wih1^T + bih1 -> bufC
    k_gemm_bt<false, false><<<dim3(8, 512), 256, 0, stream>>>(
        bufB, nullptr, nullptr, nullptr, nullptr, Wih + FB * FB, bih + FB,
        bufC, nullptr, NB * TB, FB, FB);

    // 5. scan layer 1: bufC -> bufA (h2 sequence; bufA's xw1 is dead)
    k_scan<<<64, 512, 0, stream>>>(WT + FB * FB, bufC, bhh + FB, bufA);

    // 6. last-row weighted average over time -> outs
    k_wavg<<<64, 512, 0, stream>>>(bufA, lat, lon, ut, outs);

    // 7. pre = outs @ W_lin^T + b_lin -> both tuple outputs
    k_gemm_bt<false, true><<<dim3((NPOI + 63) / 64, 1), 256, 0, stream>>>(
        outs, nullptr, nullptr, nullptr, nullptr, Wlin, blin,
        out, out + (size_t)NB * NPOI, NB, NPOI, FB);
}